// Round 12
// baseline (859.017 us; speedup 1.0000x reference)
//
#include <hip/hip_runtime.h>
#include <hip/hip_cooperative_groups.h>

namespace cg = cooperative_groups;

// ---------------------------------------------------------------------------
// Round 12: fuse the 5 layer kernels into one persistent cooperative kernel
// (grid.sync between layers). Eliminates 4 dispatch drain/ramp cycles and
// gives per-XCD L2 reuse of edata across layers (persistent blocks process
// the same 256-item tiles each layer; tile-strided so quad/wave alignment is
// identical to r11). All inner loop bodies byte-identical to round 11.
// bin/build/emb pipeline unchanged.
// ---------------------------------------------------------------------------

#define BCAP 4608      // bucket capacity: mean 4096 + 8 sigma
#define NBMAX 400

__device__ __forceinline__ float sus_f(float x) {
    return x > 0.0f ? __expf(-1.0f / x) : 0.0f;
}

__device__ __forceinline__ float uload(const float* p) {
    return __uint_as_float(__builtin_amdgcn_readfirstlane(__float_as_uint(*p)));
}

// --- pass 1: coarse binning, 4 B packed {src<<8 | dst&255}; block 0 also
// computes G[k][u][c] = sum_w fc3_w2[k][u*16+w] * conv_w[c][w] ---------------
__global__ __launch_bounds__(256) void k_bin(
    const int* __restrict__ src, const int* __restrict__ dst,
    int* __restrict__ gcur, int* __restrict__ ptmp,
    const float* __restrict__ fc3w2, const float* __restrict__ cw,
    float* __restrict__ gbuf,
    int nedges, int nb)
{
    __shared__ int cnt[NBMAX];
    __shared__ int gb[NBMAX];
    for (int b = threadIdx.x; b < nb; b += 256) cnt[b] = 0;
    __syncthreads();

    int base = blockIdx.x * 2048 + threadIdx.x * 8;
    int pk[8]; int bk[8]; short r[8];
    int ss[8], dd[8];
    if (base + 7 < nedges) {
        int4 s0 = *(const int4*)&src[base];
        int4 s1 = *(const int4*)&src[base + 4];
        int4 d0 = *(const int4*)&dst[base];
        int4 d1 = *(const int4*)&dst[base + 4];
        ss[0]=s0.x; ss[1]=s0.y; ss[2]=s0.z; ss[3]=s0.w;
        ss[4]=s1.x; ss[5]=s1.y; ss[6]=s1.z; ss[7]=s1.w;
        dd[0]=d0.x; dd[1]=d0.y; dd[2]=d0.z; dd[3]=d0.w;
        dd[4]=d1.x; dd[5]=d1.y; dd[6]=d1.z; dd[7]=d1.w;
        #pragma unroll
        for (int i = 0; i < 8; ++i) {
            int b = dd[i] >> 8;
            bk[i] = b;
            pk[i] = (ss[i] << 8) | (dd[i] & 255);
            r[i] = (short)atomicAdd(&cnt[b], 1);
        }
    } else {
        #pragma unroll
        for (int i = 0; i < 8; ++i) {
            int e = base + i;
            if (e < nedges) {
                int s = src[e], t = dst[e];
                int b = t >> 8;
                bk[i] = b;
                pk[i] = (s << 8) | (t & 255);
                r[i] = (short)atomicAdd(&cnt[b], 1);
            } else bk[i] = -1;
        }
    }
    __syncthreads();
    for (int b = threadIdx.x; b < nb; b += 256) {
        int c = cnt[b];
        gb[b] = c > 0 ? atomicAdd(&gcur[b], c) : 0;
    }
    __syncthreads();
    #pragma unroll
    for (int i = 0; i < 8; ++i) {
        if (bk[i] >= 0) {
            int p = gb[bk[i]] + (int)r[i];
            if (p < BCAP)   // statistically impossible overflow guard
                ptmp[bk[i] * BCAP + p] = pk[i];
        }
    }

    // fold in the tiny G-precompute (one block, independent of binning data)
    if (blockIdx.x == 0 && threadIdx.x < 128) {
        int idx = threadIdx.x;          // k*8 + u*2 + c
        int k = idx >> 3, u = (idx >> 1) & 3, c = idx & 1;
        float s = 0.0f;
        #pragma unroll
        for (int w = 0; w < 16; ++w)
            s = fmaf(fc3w2[k * 64 + u * 16 + w], cw[c * 16 + w], s);
        gbuf[idx] = s;
    }
}

// --- pass 2: per-bucket histogram/scan/permute (all in LDS, coalesced out) ---
__global__ __launch_bounds__(256) void k_build(
    const int* __restrict__ gcur, const int* __restrict__ ptmp,
    int* __restrict__ pidx, int2* __restrict__ offs2,
    int n, int nb)
{
    int b = blockIdx.x;
    int cnt = gcur[b]; if (cnt > BCAP) cnt = BCAP;

    __shared__ int stage[BCAP];
    __shared__ int perm[BCAP];
    __shared__ int deg[256];
    __shared__ int loffs[256];
    __shared__ int cur[256];

    const int* tin = ptmp + b * BCAP;
    for (int j = threadIdx.x; j < cnt; j += 256) stage[j] = tin[j];
    deg[threadIdx.x] = 0;
    __syncthreads();

    for (int j = threadIdx.x; j < cnt; j += 256)
        atomicAdd(&deg[stage[j] & 255], 1);
    __syncthreads();

    // exclusive scan deg -> loffs
    {
        int t = threadIdx.x;
        int v = deg[t];
        loffs[t] = v; __syncthreads();
        for (int off = 1; off < 256; off <<= 1) {
            int val = (t >= off) ? loffs[t - off] : 0;
            __syncthreads();
            loffs[t] += val;
            __syncthreads();
        }
        int incl = loffs[t];
        __syncthreads();
        loffs[t] = incl - v;
        cur[t] = incl - v;
        __syncthreads();
    }

    {
        int nid0 = b << 8;
        int nn = n - nid0; if (nn > 256) nn = 256;
        int t = threadIdx.x;
        if (t < nn) {
            int st = b * BCAP + loffs[t];
            offs2[nid0 + t] = make_int2(st, st + deg[t]);
        }
    }

    for (int j = threadIdx.x; j < cnt; j += 256) {
        int pkd = stage[j];
        perm[atomicAdd(&cur[pkd & 255], 1)] = pkd;
    }
    __syncthreads();

    int* tout = pidx + b * BCAP;
    for (int j = threadIdx.x; j < cnt; j += 256) tout[j] = perm[j];
}

// --- pass 3: edge-parallel emb, coalesced 16 B record writes -----------------
__global__ __launch_bounds__(256) void k_emb(
    const float* __restrict__ pos, const int* __restrict__ gcur,
    const int* __restrict__ pidx, float4* __restrict__ ebuf)
{
    int b = blockIdx.y;
    int j = blockIdx.x * 256 + threadIdx.x;
    if (j >= gcur[b]) return;
    int pkd = pidx[b * BCAP + j];
    int s = pkd >> 8;
    int t = (b << 8) | (pkd & 255);
    float dx = pos[3 * t + 0] - pos[3 * s + 0];
    float dy = pos[3 * t + 1] - pos[3 * s + 1];
    float dz = pos[3 * t + 2] - pos[3 * s + 2];
    float d = sqrtf(dx * dx + dy * dy + dz * dz);
    const float C = 1.14136f * 7.3890560989306495f; // 1.14136 * e^2
    float e0, e1, e2;
    { float f = (d - 0.75f) * (1.0f / 0.75f);
      e0 = C * sus_f(f + 1.0f) * sus_f(1.0f - f); }
    { float f = (d - 1.50f) * (1.0f / 0.75f);
      e1 = C * sus_f(f + 1.0f) * sus_f(1.0f - f); }
    { float f = (d - 2.25f) * (1.0f / 0.75f);
      e2 = C * sus_f(f + 1.0f) * sus_f(1.0f - f); }
    ebuf[(size_t)b * BCAP + j] = make_float4(__int_as_float(s), e0, e1, e2);
}

// --- fused layers: persistent cooperative kernel, grid.sync between layers ---
// Tiles of 256 work items (4 per node) strided by gridDim -> quad lanes stay
// wave-aligned exactly as r11; each block re-touches the same edata slices
// every layer (XCD-L2 reuse).
__global__ __launch_bounds__(256, 4) void k_layers(
    const float* __restrict__ feat, const float4* __restrict__ edata,
    const int2* __restrict__ offs2,
    const float* __restrict__ fc1w1, const float* __restrict__ fc1w2,
    const float* __restrict__ corew1, const float* __restrict__ corew2,
    const float* __restrict__ fc3w1, const float* __restrict__ gbuf,
    const float* __restrict__ cb,
    float* __restrict__ xa, float* __restrict__ xb,
    float* __restrict__ out, int n)
{
    __shared__ float lw[16 * 20];
    cg::grid_group grid = cg::this_grid();
    const int items = 4 * n;
    const int ntiles = (items + 255) >> 8;
    const int t = threadIdx.x & 3;

    // ---------------- layer 1 (feat -> xa) ----------------
    if (threadIdx.x < 192) {
        int k = threadIdx.x / 12, r = threadIdx.x % 12;
        lw[k * 20 + r] = fc1w2[k * 12 + r];
    }
    __syncthreads();
    {
        float w1r[3][16];
        #pragma unroll
        for (int j = 0; j < 3; ++j)
            #pragma unroll
            for (int k = 0; k < 16; ++k) w1r[j][k] = uload(&fc1w1[j * 16 + k]);

        for (int tile = blockIdx.x; tile < ntiles; tile += gridDim.x) {
            int it = (tile << 8) + threadIdx.x;
            if (it >= items) continue;
            int nd = it >> 2;

            float O[16][3];
            #pragma unroll
            for (int k = 0; k < 16; ++k)
                #pragma unroll
                for (int u = 0; u < 3; ++u) O[k][u] = 0.0f;

            int2 se = offs2[nd];
            for (int e = se.x + t; e < se.y; e += 4) {
                float4 ed = edata[e];
                int s = __float_as_int(ed.x);
                float f0 = feat[3 * s + 0], f1 = feat[3 * s + 1], f2 = feat[3 * s + 2];
                #pragma unroll
                for (int k = 0; k < 16; ++k) {
                    float a = fmaf(ed.y, w1r[0][k], fmaf(ed.z, w1r[1][k], ed.w * w1r[2][k]));
                    float h = a > 0.0f ? a : 0.0f;
                    O[k][0] = fmaf(h, f0, O[k][0]);
                    O[k][1] = fmaf(h, f1, O[k][1]);
                    O[k][2] = fmaf(h, f2, O[k][2]);
                }
            }

            float p0 = 0.f, p1 = 0.f, p2 = 0.f, p3 = 0.f;
            #pragma unroll
            for (int k = 0; k < 16; ++k)
                #pragma unroll
                for (int u = 0; u < 3; ++u) {
                    const float4 q = *(const float4*)&lw[k * 20 + u * 4];
                    float o = O[k][u];
                    p0 = fmaf(o, q.x, p0); p1 = fmaf(o, q.y, p1);
                    p2 = fmaf(o, q.z, p2); p3 = fmaf(o, q.w, p3);
                }
            p0 += __shfl_xor(p0, 1); p1 += __shfl_xor(p1, 1);
            p2 += __shfl_xor(p2, 1); p3 += __shfl_xor(p3, 1);
            p0 += __shfl_xor(p0, 2); p1 += __shfl_xor(p1, 2);
            p2 += __shfl_xor(p2, 2); p3 += __shfl_xor(p3, 2);
            if (t == 0) {
                const float S = 0.051031036307982884f; // sqrt2/sqrt3/16
                float4 o; o.x = p0 * S; o.y = p1 * S; o.z = p2 * S; o.w = p3 * S;
                ((float4*)xa)[nd] = o;
            }
        }
    }
    grid.sync();

    // ---------------- core layers (xa<->xb) ----------------
    for (int c = 0; c < 3; ++c) {
        const float*  w1p  = corew1 + 48 * c;
        const float*  w2p  = corew2 + 768 * c;
        const float4* xin  = (const float4*)((c == 1) ? xb : xa);
        float*        xout = (c == 1) ? xa : xb;

        {
            int k = threadIdx.x >> 4, r = threadIdx.x & 15;
            lw[k * 20 + r] = w2p[k * 48 + r];
        }
        __syncthreads();

        float w1r[3][16];
        #pragma unroll
        for (int j = 0; j < 3; ++j)
            #pragma unroll
            for (int k = 0; k < 16; ++k) w1r[j][k] = uload(&w1p[j * 16 + k]);

        for (int tile = blockIdx.x; tile < ntiles; tile += gridDim.x) {
            int it = (tile << 8) + threadIdx.x;
            if (it >= items) continue;
            int nd = it >> 2;

            float O[16][4];
            #pragma unroll
            for (int k = 0; k < 16; ++k)
                #pragma unroll
                for (int u = 0; u < 4; ++u) O[k][u] = 0.0f;

            int2 se = offs2[nd];
            for (int e = se.x + t; e < se.y; e += 4) {
                float4 ed = edata[e];
                int s = __float_as_int(ed.x);
                float4 x = xin[s];
                #pragma unroll
                for (int k = 0; k < 16; ++k) {
                    float a = fmaf(ed.y, w1r[0][k], fmaf(ed.z, w1r[1][k], ed.w * w1r[2][k]));
                    float h = a > 0.0f ? a : 0.0f;
                    O[k][0] = fmaf(h, x.x, O[k][0]);
                    O[k][1] = fmaf(h, x.y, O[k][1]);
                    O[k][2] = fmaf(h, x.z, O[k][2]);
                    O[k][3] = fmaf(h, x.w, O[k][3]);
                }
            }

            float p0 = 0.f, p1 = 0.f, p2 = 0.f, p3 = 0.f;
            #pragma unroll
            for (int k = 0; k < 16; ++k)
                #pragma unroll
                for (int u = 0; u < 4; ++u) {
                    const float4 q = *(const float4*)&lw[k * 20 + u * 4];
                    float o = O[k][u];
                    p0 = fmaf(o, q.x, p0); p1 = fmaf(o, q.y, p1);
                    p2 = fmaf(o, q.z, p2); p3 = fmaf(o, q.w, p3);
                }
            p0 += __shfl_xor(p0, 1); p1 += __shfl_xor(p1, 1);
            p2 += __shfl_xor(p2, 1); p3 += __shfl_xor(p3, 1);
            p0 += __shfl_xor(p0, 2); p1 += __shfl_xor(p1, 2);
            p2 += __shfl_xor(p2, 2); p3 += __shfl_xor(p3, 2);
            if (t == 0) {
                const float S = 0.04419417382415922f; // sqrt2*0.5/16
                float4 o; o.x = p0 * S; o.y = p1 * S; o.z = p2 * S; o.w = p3 * S;
                ((float4*)xout)[nd] = o;
            }
        }
        grid.sync();
    }

    // ---------------- fc3 + folded 1x1 conv (xb -> out) ----------------
    if (threadIdx.x < 128) lw[threadIdx.x] = gbuf[threadIdx.x];
    __syncthreads();
    {
        const float4* xin = (const float4*)xb;
        float w1r[3][16];
        #pragma unroll
        for (int j = 0; j < 3; ++j)
            #pragma unroll
            for (int k = 0; k < 16; ++k) w1r[j][k] = uload(&fc3w1[j * 16 + k]);

        for (int tile = blockIdx.x; tile < ntiles; tile += gridDim.x) {
            int it = (tile << 8) + threadIdx.x;
            if (it >= items) continue;
            int nd = it >> 2;

            float O[16][4];
            #pragma unroll
            for (int k = 0; k < 16; ++k)
                #pragma unroll
                for (int u = 0; u < 4; ++u) O[k][u] = 0.0f;

            int2 se = offs2[nd];
            for (int e = se.x + t; e < se.y; e += 4) {
                float4 ed = edata[e];
                int s = __float_as_int(ed.x);
                float4 x = xin[s];
                #pragma unroll
                for (int k = 0; k < 16; ++k) {
                    float a = fmaf(ed.y, w1r[0][k], fmaf(ed.z, w1r[1][k], ed.w * w1r[2][k]));
                    float h = a > 0.0f ? a : 0.0f;
                    O[k][0] = fmaf(h, x.x, O[k][0]);
                    O[k][1] = fmaf(h, x.y, O[k][1]);
                    O[k][2] = fmaf(h, x.z, O[k][2]);
                    O[k][3] = fmaf(h, x.w, O[k][3]);
                }
            }

            float a0 = 0.f, a1 = 0.f;
            #pragma unroll
            for (int k = 0; k < 16; ++k)
                #pragma unroll
                for (int u = 0; u < 4; ++u) {
                    float o = O[k][u];
                    const float2 q = *(const float2*)&lw[(k * 4 + u) * 2];
                    a0 = fmaf(o, q.x, a0);
                    a1 = fmaf(o, q.y, a1);
                }
            a0 += __shfl_xor(a0, 1); a1 += __shfl_xor(a1, 1);
            a0 += __shfl_xor(a0, 2); a1 += __shfl_xor(a1, 2);
            if (t == 0) {
                const float S = 0.04419417382415922f;
                float2 o; o.x = fmaf(a0, S, cb[0]); o.y = fmaf(a1, S, cb[1]);
                ((float2*)out)[nd] = o;
            }
        }
    }
}

// ---------------------------------------------------------------------------

extern "C" void kernel_launch(void* const* d_in, const int* in_sizes, int n_in,
                              void* d_out, int out_size, void* d_ws, size_t ws_size,
                              hipStream_t stream) {
    const float* pos     = (const float*)d_in[0];
    const float* feat    = (const float*)d_in[1];
    const int*   esrc    = (const int*)d_in[2];
    const int*   edst    = (const int*)d_in[3];
    const float* fc1_w1  = (const float*)d_in[4];
    const float* fc1_w2  = (const float*)d_in[5];
    const float* core_w1 = (const float*)d_in[6];
    const float* core_w2 = (const float*)d_in[7];
    const float* fc3_w1  = (const float*)d_in[8];
    const float* fc3_w2  = (const float*)d_in[9];
    const float* conv_w  = (const float*)d_in[10];
    const float* conv_b  = (const float*)d_in[11];
    float* out = (float*)d_out;

    const int E = in_sizes[2];          // 1600000
    const int N = in_sizes[0] / 3;      // 100000
    const int nb = (N + 255) >> 8;      // 391

    float4* ebuf = (float4*)d_ws;                        // nb*BCAP float4
    int* ptmp  = (int*)(ebuf + (size_t)nb * BCAP);       // nb*BCAP int
    int* pidx  = ptmp + (size_t)nb * BCAP;               // nb*BCAP int
    float* xa  = (float*)(pidx + (size_t)nb * BCAP);     // 4N
    float* xb  = xa + (size_t)4 * N;                     // 4N
    int2* offs2 = (int2*)(xb + (size_t)4 * N);           // N
    int* gcur  = (int*)(offs2 + N);                      // nb
    float* gbuf = (float*)(gcur + ((nb + 3) & ~3));      // 128

    hipMemsetAsync(gcur, 0, (size_t)nb * sizeof(int), stream);
    k_bin<<<(E + 2047) / 2048, 256, 0, stream>>>(esrc, edst, gcur, ptmp,
                                                 fc3_w2, conv_w, gbuf, E, nb);
    k_build<<<nb, 256, 0, stream>>>(gcur, ptmp, pidx, offs2, N, nb);
    {
        dim3 eg(BCAP / 256, nb);
        k_emb<<<eg, 256, 0, stream>>>(pos, gcur, pidx, ebuf);
    }

    // fused cooperative layer kernel
    {
        int nbpc = 0;
        hipOccupancyMaxActiveBlocksPerMultiprocessor(
            &nbpc, reinterpret_cast<const void*>(k_layers), 256, 0);
        if (nbpc < 1) nbpc = 1;
        int ntiles = (4 * N + 255) / 256;
        int gsize = nbpc * 256;            // 256 CUs on MI355X
        if (gsize > ntiles) gsize = ntiles;

        void* kargs[] = {
            (void*)&feat, (void*)&ebuf, (void*)&offs2,
            (void*)&fc1_w1, (void*)&fc1_w2,
            (void*)&core_w1, (void*)&core_w2,
            (void*)&fc3_w1, (void*)&gbuf, (void*)&conv_b,
            (void*)&xa, (void*)&xb, (void*)&out, (void*)&N
        };
        hipLaunchCooperativeKernel(reinterpret_cast<const void*>(k_layers),
                                   dim3(gsize), dim3(256), kargs, 0, stream);
    }
}

// Round 14
// 236.453 us; speedup vs baseline: 3.6329x; 3.6329x over previous
//
#include <hip/hip_runtime.h>

// ---------------------------------------------------------------------------
// Round 14: restore the round-11 champion (236.8 us) verbatim. The fused
// cooperative-kernel direction (r12/r13) is abandoned: r12 spilled under a
// forced VGPR cap (1.9 GB scratch traffic), and r13's hipLaunchCooperativeKernel
// silently did not execute under the harness graph capture (output unwritten,
// absmax=454 = stub signature). r11 structure: binned CSR build (k_bin 4B
// packed -> k_build LDS permute -> k_emb edge-parallel emb) + 5 layer
// dispatches (edge-split quads, partial outer product O[16][u], LDS-W2
// epilogue, fc3 with 1x1-conv folded into G).
// ---------------------------------------------------------------------------

#define BCAP 4608      // bucket capacity: mean 4096 + 8 sigma
#define NBMAX 400

__device__ __forceinline__ float sus_f(float x) {
    return x > 0.0f ? __expf(-1.0f / x) : 0.0f;
}

__device__ __forceinline__ float uload(const float* p) {
    return __uint_as_float(__builtin_amdgcn_readfirstlane(__float_as_uint(*p)));
}

// --- pass 1: coarse binning, 4 B packed {src<<8 | dst&255}; block 0 also
// computes G[k][u][c] = sum_w fc3_w2[k][u*16+w] * conv_w[c][w] ---------------
__global__ __launch_bounds__(256) void k_bin(
    const int* __restrict__ src, const int* __restrict__ dst,
    int* __restrict__ gcur, int* __restrict__ ptmp,
    const float* __restrict__ fc3w2, const float* __restrict__ cw,
    float* __restrict__ gbuf,
    int nedges, int nb)
{
    __shared__ int cnt[NBMAX];
    __shared__ int gb[NBMAX];
    for (int b = threadIdx.x; b < nb; b += 256) cnt[b] = 0;
    __syncthreads();

    int base = blockIdx.x * 2048 + threadIdx.x * 8;
    int pk[8]; int bk[8]; short r[8];
    int ss[8], dd[8];
    if (base + 7 < nedges) {
        int4 s0 = *(const int4*)&src[base];
        int4 s1 = *(const int4*)&src[base + 4];
        int4 d0 = *(const int4*)&dst[base];
        int4 d1 = *(const int4*)&dst[base + 4];
        ss[0]=s0.x; ss[1]=s0.y; ss[2]=s0.z; ss[3]=s0.w;
        ss[4]=s1.x; ss[5]=s1.y; ss[6]=s1.z; ss[7]=s1.w;
        dd[0]=d0.x; dd[1]=d0.y; dd[2]=d0.z; dd[3]=d0.w;
        dd[4]=d1.x; dd[5]=d1.y; dd[6]=d1.z; dd[7]=d1.w;
        #pragma unroll
        for (int i = 0; i < 8; ++i) {
            int b = dd[i] >> 8;
            bk[i] = b;
            pk[i] = (ss[i] << 8) | (dd[i] & 255);
            r[i] = (short)atomicAdd(&cnt[b], 1);
        }
    } else {
        #pragma unroll
        for (int i = 0; i < 8; ++i) {
            int e = base + i;
            if (e < nedges) {
                int s = src[e], t = dst[e];
                int b = t >> 8;
                bk[i] = b;
                pk[i] = (s << 8) | (t & 255);
                r[i] = (short)atomicAdd(&cnt[b], 1);
            } else bk[i] = -1;
        }
    }
    __syncthreads();
    for (int b = threadIdx.x; b < nb; b += 256) {
        int c = cnt[b];
        gb[b] = c > 0 ? atomicAdd(&gcur[b], c) : 0;
    }
    __syncthreads();
    #pragma unroll
    for (int i = 0; i < 8; ++i) {
        if (bk[i] >= 0) {
            int p = gb[bk[i]] + (int)r[i];
            if (p < BCAP)   // statistically impossible overflow guard
                ptmp[bk[i] * BCAP + p] = pk[i];
        }
    }

    // fold in the tiny G-precompute (one block, independent of binning data)
    if (blockIdx.x == 0 && threadIdx.x < 128) {
        int idx = threadIdx.x;          // k*8 + u*2 + c
        int k = idx >> 3, u = (idx >> 1) & 3, c = idx & 1;
        float s = 0.0f;
        #pragma unroll
        for (int w = 0; w < 16; ++w)
            s = fmaf(fc3w2[k * 64 + u * 16 + w], cw[c * 16 + w], s);
        gbuf[idx] = s;
    }
}

// --- pass 2: per-bucket histogram/scan/permute (all in LDS, coalesced out) ---
__global__ __launch_bounds__(256) void k_build(
    const int* __restrict__ gcur, const int* __restrict__ ptmp,
    int* __restrict__ pidx, int2* __restrict__ offs2,
    int n, int nb)
{
    int b = blockIdx.x;
    int cnt = gcur[b]; if (cnt > BCAP) cnt = BCAP;

    __shared__ int stage[BCAP];
    __shared__ int perm[BCAP];
    __shared__ int deg[256];
    __shared__ int loffs[256];
    __shared__ int cur[256];

    const int* tin = ptmp + b * BCAP;
    for (int j = threadIdx.x; j < cnt; j += 256) stage[j] = tin[j];
    deg[threadIdx.x] = 0;
    __syncthreads();

    for (int j = threadIdx.x; j < cnt; j += 256)
        atomicAdd(&deg[stage[j] & 255], 1);
    __syncthreads();

    // exclusive scan deg -> loffs
    {
        int t = threadIdx.x;
        int v = deg[t];
        loffs[t] = v; __syncthreads();
        for (int off = 1; off < 256; off <<= 1) {
            int val = (t >= off) ? loffs[t - off] : 0;
            __syncthreads();
            loffs[t] += val;
            __syncthreads();
        }
        int incl = loffs[t];
        __syncthreads();
        loffs[t] = incl - v;
        cur[t] = incl - v;
        __syncthreads();
    }

    {
        int nid0 = b << 8;
        int nn = n - nid0; if (nn > 256) nn = 256;
        int t = threadIdx.x;
        if (t < nn) {
            int st = b * BCAP + loffs[t];
            offs2[nid0 + t] = make_int2(st, st + deg[t]);
        }
    }

    for (int j = threadIdx.x; j < cnt; j += 256) {
        int pkd = stage[j];
        perm[atomicAdd(&cur[pkd & 255], 1)] = pkd;
    }
    __syncthreads();

    int* tout = pidx + b * BCAP;
    for (int j = threadIdx.x; j < cnt; j += 256) tout[j] = perm[j];
}

// --- pass 3: edge-parallel emb, coalesced 16 B record writes -----------------
__global__ __launch_bounds__(256) void k_emb(
    const float* __restrict__ pos, const int* __restrict__ gcur,
    const int* __restrict__ pidx, float4* __restrict__ ebuf)
{
    int b = blockIdx.y;
    int j = blockIdx.x * 256 + threadIdx.x;
    if (j >= gcur[b]) return;
    int pkd = pidx[b * BCAP + j];
    int s = pkd >> 8;
    int t = (b << 8) | (pkd & 255);
    float dx = pos[3 * t + 0] - pos[3 * s + 0];
    float dy = pos[3 * t + 1] - pos[3 * s + 1];
    float dz = pos[3 * t + 2] - pos[3 * s + 2];
    float d = sqrtf(dx * dx + dy * dy + dz * dz);
    const float C = 1.14136f * 7.3890560989306495f; // 1.14136 * e^2
    float e0, e1, e2;
    { float f = (d - 0.75f) * (1.0f / 0.75f);
      e0 = C * sus_f(f + 1.0f) * sus_f(1.0f - f); }
    { float f = (d - 1.50f) * (1.0f / 0.75f);
      e1 = C * sus_f(f + 1.0f) * sus_f(1.0f - f); }
    { float f = (d - 2.25f) * (1.0f / 0.75f);
      e2 = C * sus_f(f + 1.0f) * sus_f(1.0f - f); }
    ebuf[(size_t)b * BCAP + j] = make_float4(__int_as_float(s), e0, e1, e2);
}

// --- layers: edge-split quads, partial outer product, LDS-W2 epilogue --------

__global__ __launch_bounds__(256) void k_node_l1(
    const float* __restrict__ feat, const float4* __restrict__ edata,
    const int2* __restrict__ offs2,
    const float* __restrict__ w1, const float* __restrict__ w2,
    float* __restrict__ xout, int n)
{
    __shared__ float lw[16 * 20];
    if (threadIdx.x < 192) {
        int k = threadIdx.x / 12, r = threadIdx.x % 12;
        lw[k * 20 + r] = w2[k * 12 + r];
    }
    __syncthreads();

    int g = blockIdx.x * 256 + threadIdx.x;
    int nd = g >> 2;
    if (nd >= n) return;
    int t = g & 3;

    float w1r[3][16];   // wave-uniform -> SGPRs
    #pragma unroll
    for (int j = 0; j < 3; ++j)
        #pragma unroll
        for (int k = 0; k < 16; ++k) w1r[j][k] = uload(&w1[j * 16 + k]);

    float O[16][3];
    #pragma unroll
    for (int k = 0; k < 16; ++k)
        #pragma unroll
        for (int u = 0; u < 3; ++u) O[k][u] = 0.0f;

    int2 se = offs2[nd];
    for (int e = se.x + t; e < se.y; e += 4) {
        float4 ed = edata[e];
        int s = __float_as_int(ed.x);
        float f0 = feat[3 * s + 0], f1 = feat[3 * s + 1], f2 = feat[3 * s + 2];
        #pragma unroll
        for (int k = 0; k < 16; ++k) {
            float a = fmaf(ed.y, w1r[0][k], fmaf(ed.z, w1r[1][k], ed.w * w1r[2][k]));
            float h = a > 0.0f ? a : 0.0f;
            O[k][0] = fmaf(h, f0, O[k][0]);
            O[k][1] = fmaf(h, f1, O[k][1]);
            O[k][2] = fmaf(h, f2, O[k][2]);
        }
    }

    float p0 = 0.f, p1 = 0.f, p2 = 0.f, p3 = 0.f;
    #pragma unroll
    for (int k = 0; k < 16; ++k)
        #pragma unroll
        for (int u = 0; u < 3; ++u) {
            const float4 q = *(const float4*)&lw[k * 20 + u * 4];
            float o = O[k][u];
            p0 = fmaf(o, q.x, p0); p1 = fmaf(o, q.y, p1);
            p2 = fmaf(o, q.z, p2); p3 = fmaf(o, q.w, p3);
        }
    p0 += __shfl_xor(p0, 1); p1 += __shfl_xor(p1, 1);
    p2 += __shfl_xor(p2, 1); p3 += __shfl_xor(p3, 1);
    p0 += __shfl_xor(p0, 2); p1 += __shfl_xor(p1, 2);
    p2 += __shfl_xor(p2, 2); p3 += __shfl_xor(p3, 2);
    if (t == 0) {
        const float S = 0.051031036307982884f; // sqrt2/sqrt3/16
        float4 o; o.x = p0 * S; o.y = p1 * S; o.z = p2 * S; o.w = p3 * S;
        ((float4*)xout)[nd] = o;
    }
}

__global__ __launch_bounds__(256) void k_node_core(
    const float4* __restrict__ xin, const float4* __restrict__ edata,
    const int2* __restrict__ offs2,
    const float* __restrict__ w1, const float* __restrict__ w2,
    float* __restrict__ xout, int n)
{
    __shared__ float lw[16 * 20];
    {
        int idx = threadIdx.x;
        int k = idx >> 4, r = idx & 15;
        lw[k * 20 + r] = w2[k * 48 + r];
    }
    __syncthreads();

    int g = blockIdx.x * 256 + threadIdx.x;
    int nd = g >> 2;
    if (nd >= n) return;
    int t = g & 3;

    float w1r[3][16];   // wave-uniform -> SGPRs
    #pragma unroll
    for (int j = 0; j < 3; ++j)
        #pragma unroll
        for (int k = 0; k < 16; ++k) w1r[j][k] = uload(&w1[j * 16 + k]);

    float O[16][4];
    #pragma unroll
    for (int k = 0; k < 16; ++k)
        #pragma unroll
        for (int u = 0; u < 4; ++u) O[k][u] = 0.0f;

    int2 se = offs2[nd];
    for (int e = se.x + t; e < se.y; e += 4) {
        float4 ed = edata[e];
        int s = __float_as_int(ed.x);
        float4 x = xin[s];
        #pragma unroll
        for (int k = 0; k < 16; ++k) {
            float a = fmaf(ed.y, w1r[0][k], fmaf(ed.z, w1r[1][k], ed.w * w1r[2][k]));
            float h = a > 0.0f ? a : 0.0f;
            O[k][0] = fmaf(h, x.x, O[k][0]);
            O[k][1] = fmaf(h, x.y, O[k][1]);
            O[k][2] = fmaf(h, x.z, O[k][2]);
            O[k][3] = fmaf(h, x.w, O[k][3]);
        }
    }

    float p0 = 0.f, p1 = 0.f, p2 = 0.f, p3 = 0.f;
    #pragma unroll
    for (int k = 0; k < 16; ++k)
        #pragma unroll
        for (int u = 0; u < 4; ++u) {
            const float4 q = *(const float4*)&lw[k * 20 + u * 4];
            float o = O[k][u];
            p0 = fmaf(o, q.x, p0); p1 = fmaf(o, q.y, p1);
            p2 = fmaf(o, q.z, p2); p3 = fmaf(o, q.w, p3);
        }
    p0 += __shfl_xor(p0, 1); p1 += __shfl_xor(p1, 1);
    p2 += __shfl_xor(p2, 1); p3 += __shfl_xor(p3, 1);
    p0 += __shfl_xor(p0, 2); p1 += __shfl_xor(p1, 2);
    p2 += __shfl_xor(p2, 2); p3 += __shfl_xor(p3, 2);
    if (t == 0) {
        const float S = 0.04419417382415922f; // sqrt2*0.5/16
        float4 o; o.x = p0 * S; o.y = p1 * S; o.z = p2 * S; o.w = p3 * S;
        ((float4*)xout)[nd] = o;
    }
}

// fc3 + folded 1x1 conv via precomputed G[16][4][2].
__global__ __launch_bounds__(256) void k_node_fc3_final(
    const float4* __restrict__ xin, const float4* __restrict__ edata,
    const int2* __restrict__ offs2,
    const float* __restrict__ w1, const float* __restrict__ gbuf,
    const float* __restrict__ cb,
    float* __restrict__ out, int n)
{
    __shared__ float lg[128];
    if (threadIdx.x < 128) lg[threadIdx.x] = gbuf[threadIdx.x];
    __syncthreads();

    int g = blockIdx.x * 256 + threadIdx.x;
    int nd = g >> 2;
    if (nd >= n) return;
    int t = g & 3;

    float w1r[3][16];   // wave-uniform -> SGPRs
    #pragma unroll
    for (int j = 0; j < 3; ++j)
        #pragma unroll
        for (int k = 0; k < 16; ++k) w1r[j][k] = uload(&w1[j * 16 + k]);

    float O[16][4];
    #pragma unroll
    for (int k = 0; k < 16; ++k)
        #pragma unroll
        for (int u = 0; u < 4; ++u) O[k][u] = 0.0f;

    int2 se = offs2[nd];
    for (int e = se.x + t; e < se.y; e += 4) {
        float4 ed = edata[e];
        int s = __float_as_int(ed.x);
        float4 x = xin[s];
        #pragma unroll
        for (int k = 0; k < 16; ++k) {
            float a = fmaf(ed.y, w1r[0][k], fmaf(ed.z, w1r[1][k], ed.w * w1r[2][k]));
            float h = a > 0.0f ? a : 0.0f;
            O[k][0] = fmaf(h, x.x, O[k][0]);
            O[k][1] = fmaf(h, x.y, O[k][1]);
            O[k][2] = fmaf(h, x.z, O[k][2]);
            O[k][3] = fmaf(h, x.w, O[k][3]);
        }
    }

    float a0 = 0.f, a1 = 0.f;
    #pragma unroll
    for (int k = 0; k < 16; ++k)
        #pragma unroll
        for (int u = 0; u < 4; ++u) {
            float o = O[k][u];
            const float2 q = *(const float2*)&lg[(k * 4 + u) * 2];
            a0 = fmaf(o, q.x, a0);
            a1 = fmaf(o, q.y, a1);
        }
    a0 += __shfl_xor(a0, 1); a1 += __shfl_xor(a1, 1);
    a0 += __shfl_xor(a0, 2); a1 += __shfl_xor(a1, 2);
    if (t == 0) {
        const float S = 0.04419417382415922f;
        float2 o; o.x = fmaf(a0, S, cb[0]); o.y = fmaf(a1, S, cb[1]);
        ((float2*)out)[nd] = o;
    }
}

// ---------------------------------------------------------------------------

extern "C" void kernel_launch(void* const* d_in, const int* in_sizes, int n_in,
                              void* d_out, int out_size, void* d_ws, size_t ws_size,
                              hipStream_t stream) {
    const float* pos     = (const float*)d_in[0];
    const float* feat    = (const float*)d_in[1];
    const int*   esrc    = (const int*)d_in[2];
    const int*   edst    = (const int*)d_in[3];
    const float* fc1_w1  = (const float*)d_in[4];
    const float* fc1_w2  = (const float*)d_in[5];
    const float* core_w1 = (const float*)d_in[6];
    const float* core_w2 = (const float*)d_in[7];
    const float* fc3_w1  = (const float*)d_in[8];
    const float* fc3_w2  = (const float*)d_in[9];
    const float* conv_w  = (const float*)d_in[10];
    const float* conv_b  = (const float*)d_in[11];
    float* out = (float*)d_out;

    const int E = in_sizes[2];          // 1600000
    const int N = in_sizes[0] / 3;      // 100000
    const int nb = (N + 255) >> 8;      // 391

    float4* ebuf = (float4*)d_ws;                        // nb*BCAP float4
    int* ptmp  = (int*)(ebuf + (size_t)nb * BCAP);       // nb*BCAP int
    int* pidx  = ptmp + (size_t)nb * BCAP;               // nb*BCAP int
    float* xa  = (float*)(pidx + (size_t)nb * BCAP);     // 4N
    float* xb  = xa + (size_t)4 * N;                     // 4N
    int2* offs2 = (int2*)(xb + (size_t)4 * N);           // N
    int* gcur  = (int*)(offs2 + N);                      // nb
    float* gbuf = (float*)(gcur + ((nb + 3) & ~3));      // 128

    int g4 = (4 * N + 255) / 256;

    hipMemsetAsync(gcur, 0, (size_t)nb * sizeof(int), stream);
    k_bin<<<(E + 2047) / 2048, 256, 0, stream>>>(esrc, edst, gcur, ptmp,
                                                 fc3_w2, conv_w, gbuf, E, nb);
    k_build<<<nb, 256, 0, stream>>>(gcur, ptmp, pidx, offs2, N, nb);
    {
        dim3 eg(BCAP / 256, nb);
        k_emb<<<eg, 256, 0, stream>>>(pos, gcur, pidx, ebuf);
    }

    k_node_l1<<<g4, 256, 0, stream>>>(feat, ebuf, offs2, fc1_w1, fc1_w2, xa, N);
    k_node_core<<<g4, 256, 0, stream>>>((const float4*)xa, ebuf, offs2,
                                        core_w1 + 0, core_w2 + 0, xb, N);
    k_node_core<<<g4, 256, 0, stream>>>((const float4*)xb, ebuf, offs2,
                                        core_w1 + 48, core_w2 + 768, xa, N);
    k_node_core<<<g4, 256, 0, stream>>>((const float4*)xa, ebuf, offs2,
                                        core_w1 + 96, core_w2 + 1536, xb, N);
    k_node_fc3_final<<<g4, 256, 0, stream>>>((const float4*)xb, ebuf, offs2,
                                             fc3_w1, gbuf, conv_b, out, N);
}